// Round 6
// baseline (367.605 us; speedup 1.0000x reference)
//
#include <hip/hip_runtime.h>
#include <stdint.h>

#define M_DIM 16
#define K_DIM 4096
#define N_DIM 16384

// ws layout: [0, 65536): x_int8 packed [16][4096] bytes ; [65536, 65600): x_scale f32[16]

__device__ __forceinline__ int dot4(int a, int b, int c) {
#if __has_builtin(__builtin_amdgcn_sdot4)
    return __builtin_amdgcn_sdot4(a, b, c, false);
#else
    int s = c;
#pragma unroll
    for (int j = 0; j < 4; ++j)
        s += (int)(int8_t)(a >> (8 * j)) * (int)(int8_t)(b >> (8 * j));
    return s;
#endif
}

__device__ __forceinline__ uint32_t perm_b32(uint32_t hi, uint32_t lo, uint32_t sel) {
#if __has_builtin(__builtin_amdgcn_perm)
    return __builtin_amdgcn_perm(hi, lo, sel);
#else
    uint64_t comb = ((uint64_t)hi << 32) | lo;
    uint32_t r = 0;
#pragma unroll
    for (int j = 0; j < 4; ++j) {
        uint32_t s = (sel >> (8 * j)) & 0xff;
        uint32_t b = (s >= 8) ? 0 : (uint32_t)((comb >> (8 * s)) & 0xff);
        r |= b << (8 * j);
    }
    return r;
#endif
}

// pack low byte of 4 sign-extended int32 -> one dword [b0(x),b0(y),b0(z),b0(w)]
__device__ __forceinline__ int pack4(int4 v) {
    uint32_t p01 = perm_b32((uint32_t)v.y, (uint32_t)v.x, 0x0c0c0400u);
    uint32_t p23 = perm_b32((uint32_t)v.w, (uint32_t)v.z, 0x0c0c0400u);
    return (int)perm_b32(p23, p01, 0x05040100u);
}

__device__ __forceinline__ int clamp_q(float v) {
    int q = (int)rintf(v);
    q = q < -128 ? -128 : q;
    q = q > 127 ? 127 : q;
    return q & 255;
}

// One block per row m. 256 threads, each handles 16 consecutive floats.
__global__ __launch_bounds__(256) void quant_kernel(const float* __restrict__ x,
                                                    int8_t* __restrict__ xq,
                                                    float* __restrict__ xs) {
    const int m = blockIdx.x;
    const int t = threadIdx.x;
    const float* row = x + m * K_DIM;

    float4 v[4];
    float amax = 0.0f;
#pragma unroll
    for (int j = 0; j < 4; ++j) {
        v[j] = *(const float4*)(row + t * 16 + j * 4);
        amax = fmaxf(amax,
               fmaxf(fmaxf(fabsf(v[j].x), fabsf(v[j].y)),
                     fmaxf(fabsf(v[j].z), fabsf(v[j].w))));
    }
#pragma unroll
    for (int off = 32; off >= 1; off >>= 1)
        amax = fmaxf(amax, __shfl_xor(amax, off, 64));

    __shared__ float wmax[4];
    if ((t & 63) == 0) wmax[t >> 6] = amax;
    __syncthreads();
    const float bmax = fmaxf(fmaxf(wmax[0], wmax[1]), fmaxf(wmax[2], wmax[3]));
    const float scale = fmaxf(bmax, 1e-12f) / 127.0f;  // matches ref exactly
    if (t == 0) xs[m] = scale;

    int p[4];
#pragma unroll
    for (int j = 0; j < 4; ++j) {
        int a = clamp_q(v[j].x / scale);
        int b = clamp_q(v[j].y / scale);
        int c = clamp_q(v[j].z / scale);
        int d = clamp_q(v[j].w / scale);
        p[j] = a | (b << 8) | (c << 16) | (d << 24);
    }
    ((int4*)(xq + m * K_DIM))[t] = make_int4(p[0], p[1], p[2], p[3]);
}

// 512 threads = 8 waves; block covers 32 weight rows (wave -> 4 rows).
// Weights are SIGN-EXTENDED INT32 [N][K]. Lane l: r = l>>4 row-in-wave,
// kl = l&15 k-slot. Per outer iter i (128 k-elems), lane loads TWO ADJACENT
// int4s (32B contiguous per lane; 16 lanes cover 512B of row n), packs low
// bytes via v_perm, and reads the matching ADJACENT packed-x dword pair per
// m-row with one ds_read_b64 (32 banks, broadcast across r -> conflict-free).
__global__ __launch_bounds__(512) void gemv_kernel(const int* __restrict__ w,
                                                   const int8_t* __restrict__ xq,
                                                   const float* __restrict__ xs,
                                                   const float* __restrict__ wscale,
                                                   const float* __restrict__ bias,
                                                   float* __restrict__ out) {
    __shared__ int xlds[16384];  // packed x_int8: [m][1024 dwords] (64 KB)

    const int t = threadIdx.x;
    {
        const int4* src = (const int4*)xq;
        int4* dst = (int4*)xlds;
#pragma unroll
        for (int j = 0; j < 8; ++j)
            dst[j * 512 + t] = src[j * 512 + t];
    }
    __syncthreads();

    const int wid = t >> 6;
    const int lane = t & 63;
    const int r = lane >> 4;
    const int kl = lane & 15;
    const int n = blockIdx.x * 32 + wid * 4 + r;
    const int4* wrow = (const int4*)(w + (size_t)n * K_DIM);  // 1024 int4 per row

    int acc[16];
#pragma unroll
    for (int m2 = 0; m2 < 16; ++m2) acc[m2] = 0;

#pragma unroll 4
    for (int i = 0; i < 32; ++i) {
        // k-elems [i*128 + 8*kl, +8): two adjacent int4s
        const int4 wv0 = wrow[i * 32 + 2 * kl];
        const int4 wv1 = wrow[i * 32 + 2 * kl + 1];
        const int pw0 = pack4(wv0);
        const int pw1 = pack4(wv1);
#pragma unroll
        for (int m2 = 0; m2 < 16; ++m2) {
            const int2 xv = *(const int2*)&xlds[m2 * 1024 + i * 32 + 2 * kl];
            acc[m2] = dot4(pw1, xv.y, dot4(pw0, xv.x, acc[m2]));
        }
    }

    // butterfly reduce across the 16 k-lanes (within each 16-lane group)
#pragma unroll
    for (int m2 = 0; m2 < 16; ++m2) {
        int v = acc[m2];
        v += __shfl_xor(v, 1, 64);
        v += __shfl_xor(v, 2, 64);
        v += __shfl_xor(v, 4, 64);
        v += __shfl_xor(v, 8, 64);
        acc[m2] = v;
    }
    // lane kl takes output row m = kl
    int sel = 0;
#pragma unroll
    for (int m2 = 0; m2 < 16; ++m2)
        if (kl == m2) sel = acc[m2];

    const float y = (float)sel * xs[kl] * wscale[n] + bias[n];
    out[(size_t)kl * N_DIM + n] = y;
}

extern "C" void kernel_launch(void* const* d_in, const int* in_sizes, int n_in,
                              void* d_out, int out_size, void* d_ws, size_t ws_size,
                              hipStream_t stream) {
    const float* x      = (const float*)d_in[0];
    const int*   w      = (const int*)d_in[1];     // int8 widened to int32 by harness
    const float* wscale = (const float*)d_in[2];
    const float* bias   = (const float*)d_in[3];
    float* out = (float*)d_out;

    int8_t* xq = (int8_t*)d_ws;
    float*  xs = (float*)((char*)d_ws + 65536);

    quant_kernel<<<16, 256, 0, stream>>>(x, xq, xs);
    gemv_kernel<<<N_DIM / 32, 512, 0, stream>>>(w, xq, xs, wscale, bias, out);
}

// Round 16
// 364.295 us; speedup vs baseline: 1.0091x; 1.0091x over previous
//
#include <hip/hip_runtime.h>
#include <stdint.h>

#define M_DIM 16
#define K_DIM 4096
#define N_DIM 16384

// ws layout: [0, 65536): x_int8 packed [16][4096] bytes ; [65536, 65600): x_scale f32[16]

__device__ __forceinline__ int dot4(int a, int b, int c) {
#if __has_builtin(__builtin_amdgcn_sdot4)
    return __builtin_amdgcn_sdot4(a, b, c, false);
#else
    int s = c;
#pragma unroll
    for (int j = 0; j < 4; ++j)
        s += (int)(int8_t)(a >> (8 * j)) * (int)(int8_t)(b >> (8 * j));
    return s;
#endif
}

__device__ __forceinline__ uint32_t perm_b32(uint32_t hi, uint32_t lo, uint32_t sel) {
#if __has_builtin(__builtin_amdgcn_perm)
    return __builtin_amdgcn_perm(hi, lo, sel);
#else
    uint64_t comb = ((uint64_t)hi << 32) | lo;
    uint32_t r = 0;
#pragma unroll
    for (int j = 0; j < 4; ++j) {
        uint32_t s = (sel >> (8 * j)) & 0xff;
        uint32_t b = (s >= 8) ? 0 : (uint32_t)((comb >> (8 * s)) & 0xff);
        r |= b << (8 * j);
    }
    return r;
#endif
}

// pack low byte of 4 sign-extended int32 -> one dword [b0(x),b0(y),b0(z),b0(w)]
__device__ __forceinline__ int pack4(int4 v) {
    uint32_t p01 = perm_b32((uint32_t)v.y, (uint32_t)v.x, 0x0c0c0400u);
    uint32_t p23 = perm_b32((uint32_t)v.w, (uint32_t)v.z, 0x0c0c0400u);
    return (int)perm_b32(p23, p01, 0x05040100u);
}

__device__ __forceinline__ int clamp_q(float v) {
    int q = (int)rintf(v);
    q = q < -128 ? -128 : q;
    q = q > 127 ? 127 : q;
    return q & 255;
}

// One block per row m. 256 threads, each handles 16 consecutive floats.
__global__ __launch_bounds__(256) void quant_kernel(const float* __restrict__ x,
                                                    int8_t* __restrict__ xq,
                                                    float* __restrict__ xs) {
    const int m = blockIdx.x;
    const int t = threadIdx.x;
    const float* row = x + m * K_DIM;

    float4 v[4];
    float amax = 0.0f;
#pragma unroll
    for (int j = 0; j < 4; ++j) {
        v[j] = *(const float4*)(row + t * 16 + j * 4);
        amax = fmaxf(amax,
               fmaxf(fmaxf(fabsf(v[j].x), fabsf(v[j].y)),
                     fmaxf(fabsf(v[j].z), fabsf(v[j].w))));
    }
#pragma unroll
    for (int off = 32; off >= 1; off >>= 1)
        amax = fmaxf(amax, __shfl_xor(amax, off, 64));

    __shared__ float wmax[4];
    if ((t & 63) == 0) wmax[t >> 6] = amax;
    __syncthreads();
    const float bmax = fmaxf(fmaxf(wmax[0], wmax[1]), fmaxf(wmax[2], wmax[3]));
    const float scale = fmaxf(bmax, 1e-12f) / 127.0f;  // matches ref exactly
    if (t == 0) xs[m] = scale;

    int p[4];
#pragma unroll
    for (int j = 0; j < 4; ++j) {
        int a = clamp_q(v[j].x / scale);
        int b = clamp_q(v[j].y / scale);
        int c = clamp_q(v[j].z / scale);
        int d = clamp_q(v[j].w / scale);
        p[j] = a | (b << 8) | (c << 16) | (d << 24);
    }
    ((int4*)(xq + m * K_DIM))[t] = make_int4(p[0], p[1], p[2], p[3]);
}

// 1024 blocks x 512 threads (8 waves); block covers 16 weight rows
// (wave -> 2 rows). Split-K: xq staged in TWO 32KB phases so LDS/block = 32KB
// -> 4 blocks/CU resident = 32 waves/CU (100% occupancy, 2x in-flight loads
// vs the 64KB variant). Lane l: r = l>>5 row-in-wave, kl = l&31 k-slot.
// Per iter a lane loads one int4 (16B; 32 lanes cover 512B of row n
// contiguously), packs low bytes via v_perm, dot4s vs 16 staged m-rows.
// ds_read_b32 bank = kl -> 32 distinct banks, r-groups broadcast: conflict-free.
__global__ __launch_bounds__(512) void gemv_kernel(const int* __restrict__ w,
                                                   const int8_t* __restrict__ xq,
                                                   const float* __restrict__ xs,
                                                   const float* __restrict__ wscale,
                                                   const float* __restrict__ bias,
                                                   float* __restrict__ out) {
    __shared__ int xlds[8192];  // packed x_int8 half-K: [m][512 dwords] (32 KB)

    const int t = threadIdx.x;
    const int wid = t >> 6;
    const int lane = t & 63;
    const int r = lane >> 5;         // 0..1
    const int kl = lane & 31;        // 0..31
    const int n = blockIdx.x * 16 + wid * 2 + r;
    const int4* wrow4 = (const int4*)(w + (size_t)n * K_DIM);  // 1024 int4/row

    int acc[16];
#pragma unroll
    for (int m2 = 0; m2 < 16; ++m2) acc[m2] = 0;

    const int4* src4 = (const int4*)xq;  // [m][256] int4 per row

#pragma unroll
    for (int p = 0; p < 2; ++p) {
        if (p) __syncthreads();  // all waves done reading phase-0 data
        // stage 32KB: 2048 int4 = 512 thr x 4; row m half p = src4[m*256+p*128+d4]
        int4* dst4 = (int4*)xlds;
#pragma unroll
        for (int jj = 0; jj < 4; ++jj) {
            const int j = jj * 512 + t;
            const int m = j >> 7, d4 = j & 127;
            dst4[j] = src4[m * 256 + p * 128 + d4];
        }
        __syncthreads();

#pragma unroll 4
        for (int i = 0; i < 16; ++i) {
            // k-elems [p*2048 + i*128 + kl*4, +4)
            const int4 wv = wrow4[p * 512 + i * 32 + kl];
            const int pw = pack4(wv);
#pragma unroll
            for (int m2 = 0; m2 < 16; ++m2) {
                const int xv = xlds[m2 * 512 + i * 32 + kl];
                acc[m2] = dot4(pw, xv, acc[m2]);
            }
        }
    }

    // butterfly reduce across the 32 k-lanes (within each 32-lane group)
#pragma unroll
    for (int m2 = 0; m2 < 16; ++m2) {
        int v = acc[m2];
        v += __shfl_xor(v, 1, 64);
        v += __shfl_xor(v, 2, 64);
        v += __shfl_xor(v, 4, 64);
        v += __shfl_xor(v, 8, 64);
        v += __shfl_xor(v, 16, 64);
        acc[m2] = v;
    }
    // lane kl (<16) takes output row m = kl
    if (kl < 16) {
        int sel = 0;
#pragma unroll
        for (int m2 = 0; m2 < 16; ++m2)
            if (kl == m2) sel = acc[m2];
        const float y = (float)sel * xs[kl] * wscale[n] + bias[n];
        out[(size_t)kl * N_DIM + n] = y;
    }
}

extern "C" void kernel_launch(void* const* d_in, const int* in_sizes, int n_in,
                              void* d_out, int out_size, void* d_ws, size_t ws_size,
                              hipStream_t stream) {
    const float* x      = (const float*)d_in[0];
    const int*   w      = (const int*)d_in[1];     // int8 widened to int32 by harness
    const float* wscale = (const float*)d_in[2];
    const float* bias   = (const float*)d_in[3];
    float* out = (float*)d_out;

    int8_t* xq = (int8_t*)d_ws;
    float*  xs = (float*)((char*)d_ws + 65536);

    quant_kernel<<<16, 256, 0, stream>>>(x, xq, xs);
    gemv_kernel<<<N_DIM / 16, 512, 0, stream>>>(w, xq, xs, wscale, bias, out);
}